// Round 6
// baseline (503.054 us; speedup 1.0000x reference)
//
#include <hip/hip_runtime.h>
#include <hip/hip_fp16.h>
#include <math.h>

#define N_NODES 100000
#define N_EDGES 3200000
#define DIM 16
#define NSZ (N_NODES * DIM)

#define NPB 98          // nodes per bucket
#define NBUCK 1024      // ceil(100000/98)=1021 used; 1021..1023 empty
#define LSTR 17         // LDS row stride (DIM+1): odd -> spreads 32 banks
#define EPB 16384       // edges per partition block
#define PBLOCKS ((N_EDGES + EPB - 1) / EPB)   // 196
#define ABLK 512        // aggregate block size

typedef float nvec4 __attribute__((ext_vector_type(4)));   // native vec for nontemporal builtins

// ---- 0) state f32 -> f16 (3.2MB: fits per-XCD 4MiB L2 -> gathers become L2 hits)
__global__ __launch_bounds__(256)
void to_half(const float* __restrict__ state, __half* __restrict__ hs) {
    int i = blockIdx.x * 256 + threadIdx.x;   // one thread per 4 floats
    if (i >= NSZ / 4) return;
    nvec4 v = __builtin_nontemporal_load(&((const nvec4*)state)[i]);
    union { __half2 h[2]; float2 f; } u;
    u.h[0] = __floats2half2_rn(v.x, v.y);
    u.h[1] = __floats2half2_rn(v.z, v.w);
    ((float2*)hs)[i] = u.f;
}

// ---- 1) bucket histogram (LDS-aggregated) ----
__global__ __launch_bounds__(256)
void bucket_hist(const int* __restrict__ col, int* __restrict__ bhist) {
    __shared__ int h[NBUCK];
    for (int j = threadIdx.x; j < NBUCK; j += 256) h[j] = 0;
    __syncthreads();
    for (int e = blockIdx.x * 256 + threadIdx.x; e < N_EDGES;
         e += gridDim.x * 256)
        atomicAdd(&h[__builtin_nontemporal_load(&col[e]) / NPB], 1);
    __syncthreads();
    for (int j = threadIdx.x; j < NBUCK; j += 256)
        if (h[j]) atomicAdd(&bhist[j], h[j]);
}

// ---- 2) exclusive offsets over 1024 buckets (single block) ----
__global__ __launch_bounds__(NBUCK)
void bucket_scan(const int* __restrict__ bhist, int* __restrict__ off) {
    __shared__ int s[NBUCK];
    int t = threadIdx.x;
    int v = bhist[t];
    s[t] = v;
    __syncthreads();
    for (int d = 1; d < NBUCK; d <<= 1) {
        int u = (t >= d) ? s[t - d] : 0;
        __syncthreads();
        s[t] += u;
        __syncthreads();
    }
    off[t + 1] = s[t];
    if (t == 0) off[0] = 0;
}

// ---- 3) partition with per-(block,bucket) reservation ----
__global__ __launch_bounds__(512)
void partition_block(const int* __restrict__ row, const int* __restrict__ col,
                     const float* __restrict__ w, const int* __restrict__ off,
                     int* __restrict__ cursor,
                     unsigned long long* __restrict__ packed) {
    __shared__ int hcnt[NBUCK];
    __shared__ int base[NBUCK];
    int t = threadIdx.x;
    int e0 = blockIdx.x * EPB;
    int e1 = e0 + EPB; if (e1 > N_EDGES) e1 = N_EDGES;

    for (int j = t; j < NBUCK; j += 512) hcnt[j] = 0;
    __syncthreads();
    for (int e = e0 + t; e < e1; e += 512)
        atomicAdd(&hcnt[__builtin_nontemporal_load(&col[e]) / NPB], 1);
    __syncthreads();
    for (int j = t; j < NBUCK; j += 512) {
        int c = hcnt[j];
        base[j] = c ? (off[j] + atomicAdd(&cursor[j], c)) : 0;
        hcnt[j] = 0;               // reuse as intra-block rank cursor
    }
    __syncthreads();
    for (int e = e0 + t; e < e1; e += 512) {
        int c = __builtin_nontemporal_load(&col[e]);
        int r = __builtin_nontemporal_load(&row[e]);
        float we = __builtin_nontemporal_load(&w[e]);
        int b = c / NPB;
        int rank = atomicAdd(&hcnt[b], 1);            // LDS, fast
        unsigned hi = ((unsigned)r << 7) | (unsigned)(c - b * NPB);
        unsigned long long pv =
            ((unsigned long long)hi << 32) | __float_as_uint(we);
        __builtin_nontemporal_store(pv, &packed[base[b] + rank]);
    }
}

// ---- 4) per-bucket aggregation (f16 gathers) + fused epilogue ----
__device__ __forceinline__ void unpack_row(float4 h0, float4 h1, float* xr) {
    #pragma unroll
    for (int k = 0; k < 4; ++k) {
        float f0 = (&h0.x)[k], f1 = (&h1.x)[k];
        float2 a = __half22float2(*(__half2*)&f0);
        float2 b = __half22float2(*(__half2*)&f1);
        xr[2 * k] = a.x; xr[2 * k + 1] = a.y;
        xr[8 + 2 * k] = b.x; xr[8 + 2 * k + 1] = b.y;
    }
}

__device__ __forceinline__ void accum16(int cl, float we, const float* xr,
                                        const float* __restrict__ xc,
                                        float* __restrict__ ac) {
    const float* crow = xc + cl * LSTR;
    float* arow = ac + cl * LSTR;
    #pragma unroll
    for (int d = 0; d < 16; ++d)
        atomicAdd(&arow[d], __sinf(xr[d] - crow[d]) * we);   // ds_add_f32
}

__global__ __launch_bounds__(ABLK)
void bucket_aggregate_h(const float* __restrict__ state,
                        const __half* __restrict__ hs,
                        const int* __restrict__ off,
                        const unsigned long long* __restrict__ packed,
                        float* __restrict__ out) {
    __shared__ float xc[NPB * LSTR];
    __shared__ float ac[NPB * LSTR];
    int b = blockIdx.x;
    int n0 = b * NPB;
    int cnt = N_NODES - n0;
    if (cnt <= 0) return;
    if (cnt > NPB) cnt = NPB;
    int t = threadIdx.x;
    for (int i = t; i < cnt * DIM; i += ABLK) {
        int cl = i >> 4, d = i & 15;
        xc[cl * LSTR + d] = state[n0 * DIM + i];
    }
    for (int i = t; i < NPB * LSTR; i += ABLK) ac[i] = 0.f;
    __syncthreads();

    int beg = off[b], end = off[b + 1];
    int i = beg + t;
    for (; i + ABLK < end; i += 2 * ABLK) {
        unsigned long long p0 = __builtin_nontemporal_load(&packed[i]);
        unsigned long long p1 = __builtin_nontemporal_load(&packed[i + ABLK]);
        float w0 = __uint_as_float((unsigned)p0);
        float w1 = __uint_as_float((unsigned)p1);
        unsigned hi0 = (unsigned)(p0 >> 32), hi1 = (unsigned)(p1 >> 32);
        int cl0 = hi0 & 127, r0 = (int)(hi0 >> 7);
        int cl1 = hi1 & 127, r1 = (int)(hi1 >> 7);
        const float4* hp0 = (const float4*)(hs + r0 * DIM);   // 32B row, L2-hit
        const float4* hp1 = (const float4*)(hs + r1 * DIM);
        float4 a0 = hp0[0], a1 = hp0[1];
        float4 b0 = hp1[0], b1 = hp1[1];
        float xr0[16], xr1[16];
        unpack_row(a0, a1, xr0);
        unpack_row(b0, b1, xr1);
        accum16(cl0, w0, xr0, xc, ac);
        accum16(cl1, w1, xr1, xc, ac);
    }
    if (i < end) {
        unsigned long long p0 = __builtin_nontemporal_load(&packed[i]);
        float w0 = __uint_as_float((unsigned)p0);
        unsigned hi0 = (unsigned)(p0 >> 32);
        int cl0 = hi0 & 127, r0 = (int)(hi0 >> 7);
        const float4* hp0 = (const float4*)(hs + r0 * DIM);
        float4 a0 = hp0[0], a1 = hp0[1];
        float xr0[16];
        unpack_row(a0, a1, xr0);
        accum16(cl0, w0, xr0, xc, ac);
    }
    __syncthreads();

    for (int i2 = t; i2 < cnt * DIM; i2 += ABLK) {
        int cl = i2 >> 4, d = i2 & 15;
        float a = ac[cl * LSTR + d];
        float x = xc[cl * LSTR + d];
        float th = tanhf(a);
        int g = n0 * DIM + i2;
        __builtin_nontemporal_store(th - x, &out[0 * NSZ + g]);
        __builtin_nontemporal_store(x,      &out[1 * NSZ + g]);
        __builtin_nontemporal_store(-x,     &out[2 * NSZ + g]);
        __builtin_nontemporal_store(a,      &out[3 * NSZ + g]);
        __builtin_nontemporal_store(th,     &out[4 * NSZ + g]);
    }
}

// ---- fallback (tiny ws): round-1 atomic path ----
__global__ __launch_bounds__(256)
void edge_kernel(const float* __restrict__ state, const int* __restrict__ row,
                 const int* __restrict__ col, const float* __restrict__ w,
                 float* __restrict__ agg) {
    int idx = blockIdx.x * blockDim.x + threadIdx.x;
    if (idx >= N_EDGES * 4) return;
    int e = idx >> 2, q = idx & 3;
    int r = row[e], c = col[e];
    float we = w[e];
    const float4 xr = ((const float4*)state)[r * 4 + q];
    const float4 xcv = ((const float4*)state)[c * 4 + q];
    float* dst = agg + c * DIM + q * 4;
    atomicAdd(dst + 0, sinf(xr.x - xcv.x) * we);
    atomicAdd(dst + 1, sinf(xr.y - xcv.y) * we);
    atomicAdd(dst + 2, sinf(xr.z - xcv.z) * we);
    atomicAdd(dst + 3, sinf(xr.w - xcv.w) * we);
}

__global__ __launch_bounds__(256)
void node_kernel(const float* __restrict__ state, const float* __restrict__ agg,
                 float* __restrict__ out) {
    int idx = blockIdx.x * blockDim.x + threadIdx.x;
    if (idx >= N_NODES * 4) return;
    float4 x = ((const float4*)state)[idx];
    float4 a = ((const float4*)agg)[idx];
    float4 tv = make_float4(tanhf(a.x), tanhf(a.y), tanhf(a.z), tanhf(a.w));
    ((float4*)(out + 0 * NSZ))[idx] = make_float4(tv.x - x.x, tv.y - x.y,
                                                  tv.z - x.z, tv.w - x.w);
    ((float4*)(out + 1 * NSZ))[idx] = x;
    ((float4*)(out + 2 * NSZ))[idx] = make_float4(-x.x, -x.y, -x.z, -x.w);
    ((float4*)(out + 4 * NSZ))[idx] = tv;
}

extern "C" void kernel_launch(void* const* d_in, const int* in_sizes, int n_in,
                              void* d_out, int out_size, void* d_ws, size_t ws_size,
                              hipStream_t stream) {
    const float* state = (const float*)d_in[0];
    const int*   row   = (const int*)d_in[1];
    const int*   col   = (const int*)d_in[2];
    const float* w     = (const float*)d_in[3];
    float* out = (float*)d_out;

    size_t head_ints = (size_t)NBUCK + NBUCK + (NBUCK + 1);
    size_t packed_off = (head_ints * 4 + 15) & ~(size_t)15;
    size_t half_off   = packed_off + (size_t)N_EDGES * 8;
    size_t needed     = half_off + (size_t)NSZ * 2;

    if (ws_size >= needed) {
        int* bhist  = (int*)d_ws;            // NBUCK
        int* cursor = bhist + NBUCK;         // NBUCK
        int* off    = cursor + NBUCK;        // NBUCK+1
        unsigned long long* packed =
            (unsigned long long*)((char*)d_ws + packed_off);
        __half* hs = (__half*)((char*)d_ws + half_off);

        (void)hipMemsetAsync(d_ws, 0, (size_t)2 * NBUCK * sizeof(int), stream);
        to_half<<<(NSZ / 4 + 255) / 256, 256, 0, stream>>>(state, hs);
        bucket_hist<<<512, 256, 0, stream>>>(col, bhist);
        bucket_scan<<<1, NBUCK, 0, stream>>>(bhist, off);
        partition_block<<<PBLOCKS, 512, 0, stream>>>(row, col, w, off,
                                                     cursor, packed);
        bucket_aggregate_h<<<NBUCK, ABLK, 0, stream>>>(state, hs, off,
                                                       packed, out);
    } else {
        float* agg = out + 3 * NSZ;
        (void)hipMemsetAsync(agg, 0, NSZ * sizeof(float), stream);
        edge_kernel<<<(N_EDGES * 4 + 255) / 256, 256, 0, stream>>>(
            state, row, col, w, agg);
        node_kernel<<<(N_NODES * 4 + 255) / 256, 256, 0, stream>>>(
            state, agg, out);
    }
}

// Round 7
// 308.515 us; speedup vs baseline: 1.6306x; 1.6306x over previous
//
#include <hip/hip_runtime.h>
#include <hip/hip_fp16.h>
#include <math.h>

#define N_NODES 100000
#define N_EDGES 3200000
#define DIM 16
#define NSZ (N_NODES * DIM)

#define NPB 128         // nodes per bucket (pow2: bucket = col>>7, cl = col&127)
#define NBUCK 782       // ceil(100000/128)
#define EPB 16384       // edges per partition block
#define PBLOCKS ((N_EDGES + EPB - 1) / EPB)   // 196
#define CAP 6144        // LDS edge-sort capacity (mean 4096, max ~4.4k; 48KB)

typedef float nvec4 __attribute__((ext_vector_type(4)));

// ---- 0) state f32 -> f16 (3.2MB -> per-XCD L2 resident; halves gather bytes)
__global__ __launch_bounds__(256)
void to_half(const float* __restrict__ state, __half* __restrict__ hs) {
    int i = blockIdx.x * 256 + threadIdx.x;
    if (i >= NSZ / 4) return;
    nvec4 v = __builtin_nontemporal_load(&((const nvec4*)state)[i]);
    union { __half2 h[2]; float2 f; } u;
    u.h[0] = __floats2half2_rn(v.x, v.y);
    u.h[1] = __floats2half2_rn(v.z, v.w);
    ((float2*)hs)[i] = u.f;
}

// ---- 1) bucket histogram (LDS-aggregated) ----
__global__ __launch_bounds__(256)
void bucket_hist(const int* __restrict__ col, int* __restrict__ bhist) {
    __shared__ int h[NBUCK];
    for (int j = threadIdx.x; j < NBUCK; j += 256) h[j] = 0;
    __syncthreads();
    for (int e = blockIdx.x * 256 + threadIdx.x; e < N_EDGES;
         e += gridDim.x * 256)
        atomicAdd(&h[__builtin_nontemporal_load(&col[e]) >> 7], 1);
    __syncthreads();
    for (int j = threadIdx.x; j < NBUCK; j += 256)
        if (h[j]) atomicAdd(&bhist[j], h[j]);
}

// ---- 2) exclusive offsets over 782 buckets (single block of 1024) ----
__global__ __launch_bounds__(1024)
void bucket_scan(const int* __restrict__ bhist, int* __restrict__ off) {
    __shared__ int s[1024];
    int t = threadIdx.x;
    int v = (t < NBUCK) ? bhist[t] : 0;
    s[t] = v;
    __syncthreads();
    for (int d = 1; d < 1024; d <<= 1) {
        int u = (t >= d) ? s[t - d] : 0;
        __syncthreads();
        s[t] += u;
        __syncthreads();
    }
    if (t < NBUCK) off[t + 1] = s[t];
    if (t == 0) off[0] = 0;
}

// ---- 3) partition with per-(block,bucket) reservation ----
__global__ __launch_bounds__(512)
void partition_block(const int* __restrict__ row, const int* __restrict__ col,
                     const float* __restrict__ w, const int* __restrict__ off,
                     int* __restrict__ cursor,
                     unsigned long long* __restrict__ packed) {
    __shared__ int hcnt[NBUCK];
    __shared__ int base[NBUCK];
    int t = threadIdx.x;
    int e0 = blockIdx.x * EPB;
    int e1 = e0 + EPB; if (e1 > N_EDGES) e1 = N_EDGES;

    for (int j = t; j < NBUCK; j += 512) hcnt[j] = 0;
    __syncthreads();
    for (int e = e0 + t; e < e1; e += 512)
        atomicAdd(&hcnt[__builtin_nontemporal_load(&col[e]) >> 7], 1);
    __syncthreads();
    for (int j = t; j < NBUCK; j += 512) {
        int c = hcnt[j];
        base[j] = c ? (off[j] + atomicAdd(&cursor[j], c)) : 0;
        hcnt[j] = 0;               // reuse as intra-block rank cursor
    }
    __syncthreads();
    for (int e = e0 + t; e < e1; e += 512) {
        int c = __builtin_nontemporal_load(&col[e]);
        int r = __builtin_nontemporal_load(&row[e]);
        float we = __builtin_nontemporal_load(&w[e]);
        int b = c >> 7;
        int rank = atomicAdd(&hcnt[b], 1);            // LDS int atomic
        unsigned hi = ((unsigned)r << 7) | (unsigned)(c & 127);
        unsigned long long pv =
            ((unsigned long long)hi << 32) | __float_as_uint(we);
        __builtin_nontemporal_store(pv, &packed[base[b] + rank]);
    }
}

// ---- 4) per-bucket: in-LDS counting sort by node, then owner-computes
//         register accumulation (8-lane group per node, lane q = dim-pair q).
//         ZERO float atomics. Tiled (CAP) for robustness to big buckets. ----
__global__ __launch_bounds__(512)
void bucket_sort_aggregate(const float* __restrict__ state,
                           const __half2* __restrict__ hs2,
                           const int* __restrict__ off,
                           const unsigned long long* __restrict__ packed,
                           float* __restrict__ out) {
    __shared__ unsigned long long sbuf[CAP];       // 48KB sorted edges
    __shared__ int s_cnt[NPB], s_start[NPB], s_cur[NPB];
    int b = blockIdx.x, t = threadIdx.x;
    int g = t >> 3, q = t & 7;                     // 64 groups of 8 lanes
    int beg = off[b], end = off[b + 1];

    float2 acc[2] = {make_float2(0.f, 0.f), make_float2(0.f, 0.f)};
    float2 x2[2];
    int nn[2]; bool valid[2];
    #pragma unroll
    for (int r = 0; r < 2; ++r) {
        int j = r * 64 + g;
        int n = b * NPB + j;
        valid[r] = (n < N_NODES);
        nn[r] = n;
        x2[r] = valid[r] ? ((const float2*)state)[n * 8 + q]
                         : make_float2(0.f, 0.f);
    }

    for (int tbeg = beg; tbeg < end; tbeg += CAP) {
        int tend = tbeg + CAP; if (tend > end) tend = end;
        if (t < NPB) s_cnt[t] = 0;
        __syncthreads();
        for (int e = tbeg + t; e < tend; e += 512) {
            unsigned hi = (unsigned)(packed[e] >> 32);
            atomicAdd(&s_cnt[hi & 127], 1);
        }
        __syncthreads();
        if (t < NPB) s_start[t] = s_cnt[t];
        __syncthreads();
        for (int d = 1; d < NPB; d <<= 1) {        // Hillis-Steele over 128
            int u = 0;
            if (t < NPB && t >= d) u = s_start[t - d];
            __syncthreads();
            if (t < NPB) s_start[t] += u;
            __syncthreads();
        }
        if (t < NPB) {                             // inclusive -> exclusive
            int excl = s_start[t] - s_cnt[t];
            s_start[t] = excl;
            s_cur[t] = excl;
        }
        __syncthreads();
        for (int e = tbeg + t; e < tend; e += 512) {
            unsigned long long p = packed[e];      // L2-hot re-read
            int cl = (int)((p >> 32) & 127u);
            int pos = atomicAdd(&s_cur[cl], 1);
            sbuf[pos] = p;
        }
        __syncthreads();
        #pragma unroll
        for (int r = 0; r < 2; ++r) {
            int j = r * 64 + g;
            int e0 = s_start[j], e1 = s_cur[j];
            float2 a = acc[r], xx = x2[r];
            for (int e = e0; e < e1; ++e) {
                unsigned long long p = sbuf[e];    // 8-lane broadcast read
                float we = __uint_as_float((unsigned)p);
                int rn = (int)(p >> 39);           // row index
                float2 f = __half22float2(hs2[rn * 8 + q]);  // 4B, coalesced 32B/group
                a.x += __sinf(f.x - xx.x) * we;
                a.y += __sinf(f.y - xx.y) * we;
            }
            acc[r] = a;
        }
        __syncthreads();                           // before next tile reuses s_cnt
    }

    #pragma unroll
    for (int r = 0; r < 2; ++r) {
        if (!valid[r]) continue;
        float2 a = acc[r], xx = x2[r];
        float2 th = make_float2(tanhf(a.x), tanhf(a.y));
        int gdx = nn[r] * 8 + q;
        ((float2*)(out + 0 * (size_t)NSZ))[gdx] = make_float2(th.x - xx.x, th.y - xx.y);
        ((float2*)(out + 1 * (size_t)NSZ))[gdx] = xx;
        ((float2*)(out + 2 * (size_t)NSZ))[gdx] = make_float2(-xx.x, -xx.y);
        ((float2*)(out + 3 * (size_t)NSZ))[gdx] = a;
        ((float2*)(out + 4 * (size_t)NSZ))[gdx] = th;
    }
}

// ---- fallback (tiny ws): round-1 atomic path ----
__global__ __launch_bounds__(256)
void edge_kernel(const float* __restrict__ state, const int* __restrict__ row,
                 const int* __restrict__ col, const float* __restrict__ w,
                 float* __restrict__ agg) {
    int idx = blockIdx.x * blockDim.x + threadIdx.x;
    if (idx >= N_EDGES * 4) return;
    int e = idx >> 2, qq = idx & 3;
    int r = row[e], c = col[e];
    float we = w[e];
    const float4 xr = ((const float4*)state)[r * 4 + qq];
    const float4 xcv = ((const float4*)state)[c * 4 + qq];
    float* dst = agg + c * DIM + qq * 4;
    atomicAdd(dst + 0, sinf(xr.x - xcv.x) * we);
    atomicAdd(dst + 1, sinf(xr.y - xcv.y) * we);
    atomicAdd(dst + 2, sinf(xr.z - xcv.z) * we);
    atomicAdd(dst + 3, sinf(xr.w - xcv.w) * we);
}

__global__ __launch_bounds__(256)
void node_kernel(const float* __restrict__ state, const float* __restrict__ agg,
                 float* __restrict__ out) {
    int idx = blockIdx.x * blockDim.x + threadIdx.x;
    if (idx >= N_NODES * 4) return;
    float4 x = ((const float4*)state)[idx];
    float4 a = ((const float4*)agg)[idx];
    float4 tv = make_float4(tanhf(a.x), tanhf(a.y), tanhf(a.z), tanhf(a.w));
    ((float4*)(out + 0 * NSZ))[idx] = make_float4(tv.x - x.x, tv.y - x.y,
                                                  tv.z - x.z, tv.w - x.w);
    ((float4*)(out + 1 * NSZ))[idx] = x;
    ((float4*)(out + 2 * NSZ))[idx] = make_float4(-x.x, -x.y, -x.z, -x.w);
    ((float4*)(out + 4 * NSZ))[idx] = tv;
}

extern "C" void kernel_launch(void* const* d_in, const int* in_sizes, int n_in,
                              void* d_out, int out_size, void* d_ws, size_t ws_size,
                              hipStream_t stream) {
    const float* state = (const float*)d_in[0];
    const int*   row   = (const int*)d_in[1];
    const int*   col   = (const int*)d_in[2];
    const float* w     = (const float*)d_in[3];
    float* out = (float*)d_out;

    size_t head_ints = (size_t)NBUCK + NBUCK + (NBUCK + 1);
    size_t packed_off = (head_ints * 4 + 15) & ~(size_t)15;
    size_t half_off   = packed_off + (size_t)N_EDGES * 8;
    size_t needed     = half_off + (size_t)NSZ * 2;

    if (ws_size >= needed) {
        int* bhist  = (int*)d_ws;            // NBUCK
        int* cursor = bhist + NBUCK;         // NBUCK
        int* off    = cursor + NBUCK;        // NBUCK+1
        unsigned long long* packed =
            (unsigned long long*)((char*)d_ws + packed_off);
        __half* hs = (__half*)((char*)d_ws + half_off);

        (void)hipMemsetAsync(d_ws, 0, (size_t)2 * NBUCK * sizeof(int), stream);
        to_half<<<(NSZ / 4 + 255) / 256, 256, 0, stream>>>(state, hs);
        bucket_hist<<<512, 256, 0, stream>>>(col, bhist);
        bucket_scan<<<1, 1024, 0, stream>>>(bhist, off);
        partition_block<<<PBLOCKS, 512, 0, stream>>>(row, col, w, off,
                                                     cursor, packed);
        bucket_sort_aggregate<<<NBUCK, 512, 0, stream>>>(
            state, (const __half2*)hs, off, packed, out);
    } else {
        float* agg = out + 3 * NSZ;
        (void)hipMemsetAsync(agg, 0, NSZ * sizeof(float), stream);
        edge_kernel<<<(N_EDGES * 4 + 255) / 256, 256, 0, stream>>>(
            state, row, col, w, agg);
        node_kernel<<<(N_NODES * 4 + 255) / 256, 256, 0, stream>>>(
            state, agg, out);
    }
}

// Round 8
// 254.290 us; speedup vs baseline: 1.9783x; 1.2132x over previous
//
#include <hip/hip_runtime.h>
#include <hip/hip_fp16.h>
#include <math.h>

#define N_NODES 100000
#define N_EDGES 3200000
#define DIM 16
#define NSZ (N_NODES * DIM)

#define NPB 128         // nodes per bucket (pow2: bucket = col>>7, cl = col&127)
#define NBUCK 782       // ceil(100000/128)
#define EPB 6144        // edges per partition block (sbuf 48KB)
#define PBLOCKS ((N_EDGES + EPB - 1) / EPB)   // 521
#define CAP 6144        // aggregate LDS edge capacity

typedef float nvec4 __attribute__((ext_vector_type(4)));

// ---- 1) fused: state f32->f16 convert + bucket histogram ----
__global__ __launch_bounds__(256)
void convert_hist(const float* __restrict__ state, __half* __restrict__ hs,
                  const int* __restrict__ col, int* __restrict__ bhist) {
    __shared__ int h[NBUCK];
    for (int j = threadIdx.x; j < NBUCK; j += 256) h[j] = 0;
    // part A: convert (grid-stride over NSZ/4 float4s)
    for (int i = blockIdx.x * 256 + threadIdx.x; i < NSZ / 4;
         i += gridDim.x * 256) {
        nvec4 v = __builtin_nontemporal_load(&((const nvec4*)state)[i]);
        union { __half2 hh[2]; float2 f; } u;
        u.hh[0] = __floats2half2_rn(v.x, v.y);
        u.hh[1] = __floats2half2_rn(v.z, v.w);
        ((float2*)hs)[i] = u.f;
    }
    __syncthreads();
    // part B: histogram (grid-stride over edges)
    for (int e = blockIdx.x * 256 + threadIdx.x; e < N_EDGES;
         e += gridDim.x * 256)
        atomicAdd(&h[__builtin_nontemporal_load(&col[e]) >> 7], 1);
    __syncthreads();
    for (int j = threadIdx.x; j < NBUCK; j += 256)
        if (h[j]) atomicAdd(&bhist[j], h[j]);
}

// ---- 2) exclusive offsets over 782 buckets (single block of 1024) ----
__global__ __launch_bounds__(1024)
void bucket_scan(const int* __restrict__ bhist, int* __restrict__ off) {
    __shared__ int s[1024];
    int t = threadIdx.x;
    int v = (t < NBUCK) ? bhist[t] : 0;
    s[t] = v;
    __syncthreads();
    for (int d = 1; d < 1024; d <<= 1) {
        int u = (t >= d) ? s[t - d] : 0;
        __syncthreads();
        s[t] += u;
        __syncthreads();
    }
    if (t < NBUCK) off[t + 1] = s[t];
    if (t == 0) off[0] = 0;
}

// ---- 3) partition: in-LDS counting sort by bucket, then DENSE run writes ----
__global__ __launch_bounds__(512)
void partition_sort(const int* __restrict__ row, const int* __restrict__ col,
                    const float* __restrict__ w, const int* __restrict__ off,
                    int* __restrict__ cursor,
                    unsigned long long* __restrict__ packed) {
    __shared__ unsigned long long sbuf[EPB];   // 48KB sorted edges
    __shared__ int sc[1024];                   // scan scratch -> lstart
    __shared__ int hcnt[NBUCK];                // counts -> intra-block cursor
    __shared__ int gbase[NBUCK];               // reserved global base
    int t = threadIdx.x;
    int e0 = blockIdx.x * EPB;
    int e1 = e0 + EPB; if (e1 > N_EDGES) e1 = N_EDGES;
    int m = e1 - e0;

    for (int j = t; j < NBUCK; j += 512) hcnt[j] = 0;
    __syncthreads();
    // p1: histogram (normal loads: keep lines in L2 for the p3 re-read)
    for (int e = e0 + t; e < e1; e += 512)
        atomicAdd(&hcnt[col[e] >> 7], 1);
    __syncthreads();
    // p2: Hillis-Steele inclusive scan over padded 1024, 2 slots/thread
    sc[t]       = (t < NBUCK)       ? hcnt[t]       : 0;
    sc[t + 512] = (t + 512 < NBUCK) ? hcnt[t + 512] : 0;
    __syncthreads();
    for (int d = 1; d < 1024; d <<= 1) {
        int i1 = t, i2 = t + 512;
        int u1 = (i1 >= d) ? sc[i1 - d] : 0;
        int u2 = (i2 >= d) ? sc[i2 - d] : 0;
        __syncthreads();
        sc[i1] += u1;
        sc[i2] += u2;
        __syncthreads();
    }
    // inclusive -> exclusive in place (sc becomes lstart), reserve global, reset cur
    for (int j = t; j < NBUCK; j += 512) {
        int c = hcnt[j];
        sc[j] -= c;                       // lstart[j]
        gbase[j] = c ? (off[j] + atomicAdd(&cursor[j], c)) : 0;
        hcnt[j] = 0;                      // reuse as intra-block cursor
    }
    __syncthreads();
    // p3: re-read edges (L2-hot), scatter into LDS in bucket-sorted order
    for (int e = e0 + t; e < e1; e += 512) {
        int c = col[e];
        int b = c >> 7;
        int pos = sc[b] + atomicAdd(&hcnt[b], 1);
        unsigned hi = ((unsigned)row[e] << 7) | (unsigned)(c & 127);
        sbuf[pos] = ((unsigned long long)hi << 32) | __float_as_uint(w[e]);
    }
    __syncthreads();
    // p4: linear sweep -> dense global runs; bucket via binary search in lstart
    for (int s = t; s < m; s += 512) {
        int lo = 0, hi = NBUCK - 1;
        while (lo < hi) {                  // largest b with lstart[b] <= s
            int mid = (lo + hi + 1) >> 1;
            if (sc[mid] <= s) lo = mid; else hi = mid - 1;
        }
        __builtin_nontemporal_store(sbuf[s], &packed[gbase[lo] + (s - sc[lo])]);
    }
}

// ---- 4) per-bucket: in-LDS counting sort by node, owner-computes registers ----
__global__ __launch_bounds__(512)
void bucket_sort_aggregate(const float* __restrict__ state,
                           const __half2* __restrict__ hs2,
                           const int* __restrict__ off,
                           const unsigned long long* __restrict__ packed,
                           float* __restrict__ out) {
    __shared__ unsigned long long sbuf[CAP];       // 48KB sorted edges
    __shared__ int s_cnt[NPB], s_start[NPB], s_cur[NPB];
    int b = blockIdx.x, t = threadIdx.x;
    int g = t >> 3, q = t & 7;                     // 64 groups of 8 lanes
    int beg = off[b], end = off[b + 1];

    float2 acc[2] = {make_float2(0.f, 0.f), make_float2(0.f, 0.f)};
    float2 x2[2];
    int nn[2]; bool valid[2];
    #pragma unroll
    for (int r = 0; r < 2; ++r) {
        int j = r * 64 + g;
        int n = b * NPB + j;
        valid[r] = (n < N_NODES);
        nn[r] = n;
        x2[r] = valid[r] ? ((const float2*)state)[n * 8 + q]
                         : make_float2(0.f, 0.f);
    }

    for (int tbeg = beg; tbeg < end; tbeg += CAP) {
        int tend = tbeg + CAP; if (tend > end) tend = end;
        if (t < NPB) s_cnt[t] = 0;
        __syncthreads();
        for (int e = tbeg + t; e < tend; e += 512) {
            unsigned hi = (unsigned)(packed[e] >> 32);
            atomicAdd(&s_cnt[hi & 127], 1);
        }
        __syncthreads();
        if (t < NPB) s_start[t] = s_cnt[t];
        __syncthreads();
        for (int d = 1; d < NPB; d <<= 1) {        // Hillis-Steele over 128
            int u = 0;
            if (t < NPB && t >= d) u = s_start[t - d];
            __syncthreads();
            if (t < NPB) s_start[t] += u;
            __syncthreads();
        }
        if (t < NPB) {                             // inclusive -> exclusive
            int excl = s_start[t] - s_cnt[t];
            s_start[t] = excl;
            s_cur[t] = excl;
        }
        __syncthreads();
        for (int e = tbeg + t; e < tend; e += 512) {
            unsigned long long p = packed[e];      // L2-hot re-read
            int cl = (int)((p >> 32) & 127u);
            int pos = atomicAdd(&s_cur[cl], 1);
            sbuf[pos] = p;
        }
        __syncthreads();
        #pragma unroll
        for (int r = 0; r < 2; ++r) {
            int j = r * 64 + g;
            int es = s_start[j], ee = s_cur[j];
            float2 a = acc[r], xx = x2[r];
            for (int e = es; e < ee; ++e) {
                unsigned long long p = sbuf[e];    // 8-lane broadcast read
                float we = __uint_as_float((unsigned)p);
                int rn = (int)(p >> 39);           // row index
                float2 f = __half22float2(hs2[rn * 8 + q]);  // 4B, 32B/group
                a.x += __sinf(f.x - xx.x) * we;
                a.y += __sinf(f.y - xx.y) * we;
            }
            acc[r] = a;
        }
        __syncthreads();                           // before next tile reuse
    }

    #pragma unroll
    for (int r = 0; r < 2; ++r) {
        if (!valid[r]) continue;
        float2 a = acc[r], xx = x2[r];
        float2 th = make_float2(tanhf(a.x), tanhf(a.y));
        int gdx = nn[r] * 8 + q;
        ((float2*)(out + 0 * (size_t)NSZ))[gdx] = make_float2(th.x - xx.x, th.y - xx.y);
        ((float2*)(out + 1 * (size_t)NSZ))[gdx] = xx;
        ((float2*)(out + 2 * (size_t)NSZ))[gdx] = make_float2(-xx.x, -xx.y);
        ((float2*)(out + 3 * (size_t)NSZ))[gdx] = a;
        ((float2*)(out + 4 * (size_t)NSZ))[gdx] = th;
    }
}

// ---- fallback (tiny ws): round-1 atomic path ----
__global__ __launch_bounds__(256)
void edge_kernel(const float* __restrict__ state, const int* __restrict__ row,
                 const int* __restrict__ col, const float* __restrict__ w,
                 float* __restrict__ agg) {
    int idx = blockIdx.x * blockDim.x + threadIdx.x;
    if (idx >= N_EDGES * 4) return;
    int e = idx >> 2, qq = idx & 3;
    int r = row[e], c = col[e];
    float we = w[e];
    const float4 xr = ((const float4*)state)[r * 4 + qq];
    const float4 xcv = ((const float4*)state)[c * 4 + qq];
    float* dst = agg + c * DIM + qq * 4;
    atomicAdd(dst + 0, sinf(xr.x - xcv.x) * we);
    atomicAdd(dst + 1, sinf(xr.y - xcv.y) * we);
    atomicAdd(dst + 2, sinf(xr.z - xcv.z) * we);
    atomicAdd(dst + 3, sinf(xr.w - xcv.w) * we);
}

__global__ __launch_bounds__(256)
void node_kernel(const float* __restrict__ state, const float* __restrict__ agg,
                 float* __restrict__ out) {
    int idx = blockIdx.x * blockDim.x + threadIdx.x;
    if (idx >= N_NODES * 4) return;
    float4 x = ((const float4*)state)[idx];
    float4 a = ((const float4*)agg)[idx];
    float4 tv = make_float4(tanhf(a.x), tanhf(a.y), tanhf(a.z), tanhf(a.w));
    ((float4*)(out + 0 * NSZ))[idx] = make_float4(tv.x - x.x, tv.y - x.y,
                                                  tv.z - x.z, tv.w - x.w);
    ((float4*)(out + 1 * NSZ))[idx] = x;
    ((float4*)(out + 2 * NSZ))[idx] = make_float4(-x.x, -x.y, -x.z, -x.w);
    ((float4*)(out + 4 * NSZ))[idx] = tv;
}

extern "C" void kernel_launch(void* const* d_in, const int* in_sizes, int n_in,
                              void* d_out, int out_size, void* d_ws, size_t ws_size,
                              hipStream_t stream) {
    const float* state = (const float*)d_in[0];
    const int*   row   = (const int*)d_in[1];
    const int*   col   = (const int*)d_in[2];
    const float* w     = (const float*)d_in[3];
    float* out = (float*)d_out;

    size_t head_ints = (size_t)NBUCK + NBUCK + (NBUCK + 1);
    size_t packed_off = (head_ints * 4 + 15) & ~(size_t)15;
    size_t half_off   = packed_off + (size_t)N_EDGES * 8;
    size_t needed     = half_off + (size_t)NSZ * 2;

    if (ws_size >= needed) {
        int* bhist  = (int*)d_ws;            // NBUCK
        int* cursor = bhist + NBUCK;         // NBUCK
        int* off    = cursor + NBUCK;        // NBUCK+1
        unsigned long long* packed =
            (unsigned long long*)((char*)d_ws + packed_off);
        __half* hs = (__half*)((char*)d_ws + half_off);

        (void)hipMemsetAsync(d_ws, 0, (size_t)2 * NBUCK * sizeof(int), stream);
        convert_hist<<<512, 256, 0, stream>>>(state, hs, col, bhist);
        bucket_scan<<<1, 1024, 0, stream>>>(bhist, off);
        partition_sort<<<PBLOCKS, 512, 0, stream>>>(row, col, w, off,
                                                    cursor, packed);
        bucket_sort_aggregate<<<NBUCK, 512, 0, stream>>>(
            state, (const __half2*)hs, off, packed, out);
    } else {
        float* agg = out + 3 * NSZ;
        (void)hipMemsetAsync(agg, 0, NSZ * sizeof(float), stream);
        edge_kernel<<<(N_EDGES * 4 + 255) / 256, 256, 0, stream>>>(
            state, row, col, w, agg);
        node_kernel<<<(N_NODES * 4 + 255) / 256, 256, 0, stream>>>(
            state, agg, out);
    }
}